// Round 9
// baseline (3995.498 us; speedup 1.0000x reference)
//
#include <hip/hip_runtime.h>
#include <math.h>

#define BSZ 64
#define PLEN 128
#define HLEN 64
#define EDIM 300
#define HDIM 512
#define G4 2048   // 4*HDIM
#define NCLS 3

// spin guard: protocol bug degrades to wrong answer, not a hung container.
#define SPIN_CAP (1 << 18)

// 16-chunk 512-float vector layout: 16 chunks of 36 floats (32 data + 4 pad).
#define CR16 576
#define C16(f) ((((f) >> 5) * 36) + ((f) & 31))

__device__ __forceinline__ float sigf(float x) { return 1.0f / (1.0f + __expf(-x)); }
__device__ __forceinline__ float tanhfast(float x) { return 1.0f - 2.0f / (__expf(2.0f * x) + 1.0f); }

// relaxed agent-scope atomics: LLC-coherent, bypass non-coherent L1/L2
__device__ __forceinline__ unsigned long long aload64(const unsigned long long* p) {
    return __hip_atomic_load(p, __ATOMIC_RELAXED, __HIP_MEMORY_SCOPE_AGENT);
}
__device__ __forceinline__ void astore64(unsigned long long* p, unsigned long long v) {
    __hip_atomic_store(p, v, __ATOMIC_RELAXED, __HIP_MEMORY_SCOPE_AGENT);
}
__device__ __forceinline__ unsigned long long fpack2(float lo, float hi) {
    float2 v = make_float2(lo, hi);
    return *(unsigned long long*)&v;
}
__device__ __forceinline__ float2 funpack2(unsigned long long u) {
    union { unsigned long long u; float2 f; } c; c.u = u; return c.f;
}

__global__ __launch_bounds__(256) void ws_zero(unsigned long long* p) {
    p[(size_t)blockIdx.x * 256 + threadIdx.x] = 0ull;
}

// ---------------------------------------------------------------------------
// input projection GEMM: out[m][row] = emb[toks[m]] . Wih[row] + bih[row]+bhh[row]
__global__ __launch_bounds__(256) void proj_kernel(
    const int* __restrict__ toks, const float* __restrict__ emb,
    const float* __restrict__ Wih, const float* __restrict__ bih,
    const float* __restrict__ bhh, float* __restrict__ out)
{
    __shared__ float es[32 * 100];
    __shared__ float wsh[64 * 100];
    __shared__ int tks[32];
    const int m0 = blockIdx.x * 32, r0 = blockIdx.y * 64;
    const int tid = threadIdx.x;
    const int tx = tid & 15, ty = tid >> 4;
    float acc[2][4] = {{0.f, 0.f, 0.f, 0.f}, {0.f, 0.f, 0.f, 0.f}};
    if (tid < 32) tks[tid] = toks[m0 + tid];
    __syncthreads();
    for (int kc = 0; kc < 3; kc++) {
        if (kc) __syncthreads();
        for (int i = tid; i < 800; i += 256) {
            int row = i / 25, k4 = i % 25;
            ((float4*)es)[i] = ((const float4*)(emb + (size_t)tks[row] * EDIM + kc * 100))[k4];
        }
        for (int i = tid; i < 1600; i += 256) {
            int row = i / 25, k4 = i % 25;
            ((float4*)wsh)[i] = ((const float4*)(Wih + (size_t)(r0 + row) * EDIM + kc * 100))[k4];
        }
        __syncthreads();
        const float4* e0 = (const float4*)es + ty * 25;
        const float4* e1 = e0 + 16 * 25;
        const float4* w0 = (const float4*)wsh + tx * 25;
#pragma unroll
        for (int k = 0; k < 25; k++) {
            float4 ea = e0[k], eb = e1[k];
#pragma unroll
            for (int j = 0; j < 4; j++) {
                float4 w = w0[k + j * 400];
                acc[0][j] += ea.x * w.x + ea.y * w.y + ea.z * w.z + ea.w * w.w;
                acc[1][j] += eb.x * w.x + eb.y * w.y + eb.z * w.z + eb.w * w.w;
            }
        }
    }
#pragma unroll
    for (int j = 0; j < 4; j++) {
        int rr = r0 + tx + j * 16;
        float bsum = bih[rr] + bhh[rr];
        out[(size_t)(m0 + ty) * G4 + rr]      = acc[0][j] + bsum;
        out[(size_t)(m0 + ty + 16) * G4 + rr] = acc[1][j] + bsum;
    }
}

// ---------------------------------------------------------------------------
// persistent LSTM, done-word synced (R8 verbatim). 256 blocks x 256 threads.
__global__ __launch_bounds__(256, 1) void lstm_coop(
    const float* __restrict__ xp, const float* __restrict__ xh,
    const float* __restrict__ Whh1, const float* __restrict__ Whh2,
    float* __restrict__ outp, float* __restrict__ outh,
    unsigned long long* __restrict__ hA, unsigned long long* __restrict__ hB,
    unsigned long long* __restrict__ hC, unsigned long long* __restrict__ hD,
    unsigned long long* __restrict__ doneH)
{
    const int tid = threadIdx.x;
    const int ug = blockIdx.x >> 3;
    const int bg = blockIdx.x & 7;
    const int u0 = ug * 16, b0 = bg * 8;
    const int rq = tid >> 4, cc = tid & 15;

    __shared__ __align__(16) float hst[8 * CR16];
    __shared__ float gsm[64][9];

    float4 w4[32];
#pragma unroll
    for (int j = 0; j < 4; j++) {
        int rr = 4 * rq + j;
        const float4* src = (const float4*)(Whh1 +
            ((size_t)((rr >> 4) * HDIM + u0 + (rr & 15))) * HDIM) + cc * 8;
#pragma unroll
        for (int q = 0; q < 8; q++) w4[j * 8 + q] = src[q];
    }
    float creg = 0.0f;
    const int bbc = tid >> 4, uuc = tid & 15;
    unsigned long long* dn = doneH + bg * 32;

    for (int t = 0; t < PLEN + HLEN; t++) {
        const int layer2 = (t >= PLEN) ? 1 : 0;
        const int tloc = layer2 ? t - PLEN : t;
        const int T = layer2 ? HLEN : PLEN;
        const float* xproj = layer2 ? xh : xp;
        float* outseq = layer2 ? outh : outp;
        unsigned long long* wA = layer2 ? hC : hA;
        unsigned long long* wB = layer2 ? hD : hB;
        unsigned long long* hwr = (t & 1) ? wB : wA;
        const unsigned long long* hrd = (t & 1) ? wA : wB;

        float gi = 0.f, gf = 0.f, gg = 0.f, go = 0.f;
        if (tid < 128) {
            size_t xb = ((size_t)(b0 + bbc) * T + tloc) * G4 + u0 + uuc;
            gi = xproj[xb];        gf = xproj[xb + 512];
            gg = xproj[xb + 1024]; go = xproj[xb + 1536];
        }

        if (t == PLEN) {
#pragma unroll
            for (int j = 0; j < 4; j++) {
                int rr = 4 * rq + j;
                const float4* src = (const float4*)(Whh2 +
                    ((size_t)((rr >> 4) * HDIM + u0 + (rr & 15))) * HDIM) + cc * 8;
#pragma unroll
                for (int q = 0; q < 8; q++) w4[j * 8 + q] = src[q];
            }
        }
        const bool have_h = (tloc != 0);
        if (have_h) {
            if (tid < 32) {
                unsigned long long v = aload64(dn + tid);
                int guard = 0;
                while (!__all(v >= (unsigned long long)t)) {
                    if (++guard > SPIN_CAP) break;
                    __builtin_amdgcn_s_sleep(1);
                    if (v < (unsigned long long)t) v = aload64(dn + tid);
                }
            }
            __syncthreads();
            __asm__ volatile("" ::: "memory");
            const unsigned long long* src = hrd + (size_t)b0 * 256;
            unsigned long long v[8];
#pragma unroll
            for (int i = 0; i < 8; i++) v[i] = aload64(src + tid + i * 256);
#pragma unroll
            for (int i = 0; i < 8; i++) {
                int idx = tid + i * 256;
                int bb = idx >> 8, j = idx & 255;
                float2 f = funpack2(v[i]);
                *(float2*)&hst[bb * CR16 + C16(2 * j)] = f;
            }
            __syncthreads();
#pragma unroll 1
            for (int bb = 0; bb < 8; bb++) {
                const float* hb = &hst[bb * CR16 + cc * 36];
                float a0 = 0.f, a1 = 0.f, a2 = 0.f, a3 = 0.f;
#pragma unroll
                for (int q = 0; q < 8; q++) {
                    float4 hv = *(const float4*)(hb + 4 * q);
                    float4 x;
                    x = w4[q];      a0 += x.x * hv.x + x.y * hv.y + x.z * hv.z + x.w * hv.w;
                    x = w4[8 + q];  a1 += x.x * hv.x + x.y * hv.y + x.z * hv.z + x.w * hv.w;
                    x = w4[16 + q]; a2 += x.x * hv.x + x.y * hv.y + x.z * hv.z + x.w * hv.w;
                    x = w4[24 + q]; a3 += x.x * hv.x + x.y * hv.y + x.z * hv.z + x.w * hv.w;
                }
#pragma unroll
                for (int o = 1; o < 16; o <<= 1) {
                    a0 += __shfl_xor(a0, o);
                    a1 += __shfl_xor(a1, o);
                    a2 += __shfl_xor(a2, o);
                    a3 += __shfl_xor(a3, o);
                }
                if (cc == 0) {
                    gsm[4 * rq + 0][bb] = a0;
                    gsm[4 * rq + 1][bb] = a1;
                    gsm[4 * rq + 2][bb] = a2;
                    gsm[4 * rq + 3][bb] = a3;
                }
            }
        }
        __syncthreads();
        float hn = 0.f;
        if (tid < 128) {
            if (have_h) {
                gi += gsm[uuc][bbc];
                gf += gsm[16 + uuc][bbc];
                gg += gsm[32 + uuc][bbc];
                go += gsm[48 + uuc][bbc];
            }
            float cn = sigf(gf) * creg + sigf(gi) * tanhfast(gg);
            hn = sigf(go) * tanhfast(cn);
            creg = cn;
            float pr = __shfl_xor(hn, 1);
            if ((uuc & 1) == 0)
                astore64(hwr + (size_t)(b0 + bbc) * 256 + (u0 + uuc) / 2, fpack2(hn, pr));
        }
        __asm__ volatile("s_waitcnt vmcnt(0)" ::: "memory");
        __syncthreads();
        if (tid == 0) astore64(&dn[ug], (unsigned long long)(t + 1));
        if (tid < 128)
            outseq[((size_t)(b0 + bbc) * T + tloc) * HDIM + u0 + uuc] = hn;
    }
}

// ---------------------------------------------------------------------------
// generic projection GEMM: dst[b][p][h] = sum_j W[h][j] * src[b][p][j]
// src: [BSZ][T][512]; grid (BSZ, T/32, 512/64). Used for a1 (T=128, W=Wy)
// and a2q (T=64, W=Wh).
__global__ __launch_bounds__(256) void a1_kernel(
    const float* __restrict__ W, const float* __restrict__ src,
    float* __restrict__ dst, int T)
{
    __shared__ float os[32 * 132];
    __shared__ float wsh[64 * 132];
    const int b = blockIdx.x, p0 = blockIdx.y * 32, h0 = blockIdx.z * 64;
    const int tid = threadIdx.x;
    const int tx = tid & 15, ty = tid >> 4;
    float acc[2][4] = {{0.f, 0.f, 0.f, 0.f}, {0.f, 0.f, 0.f, 0.f}};
    for (int kc = 0; kc < 4; kc++) {
        if (kc) __syncthreads();
        for (int i = tid; i < 1024; i += 256) {
            int row = i >> 5, k4 = i & 31;
            ((float4*)os)[row * 33 + k4] =
                ((const float4*)(src + ((size_t)(b * T) + p0 + row) * HDIM + kc * 128))[k4];
        }
        for (int i = tid; i < 2048; i += 256) {
            int row = i >> 5, k4 = i & 31;
            ((float4*)wsh)[row * 33 + k4] =
                ((const float4*)(W + (size_t)(h0 + row) * HDIM + kc * 128))[k4];
        }
        __syncthreads();
        const float4* o0 = (const float4*)os + ty * 33;
        const float4* o1 = o0 + 16 * 33;
        const float4* w0 = (const float4*)wsh + tx * 33;
#pragma unroll
        for (int k = 0; k < 32; k++) {
            float4 ea = o0[k], eb = o1[k];
#pragma unroll
            for (int j = 0; j < 4; j++) {
                float4 w = w0[k + j * 528];
                acc[0][j] += ea.x * w.x + ea.y * w.y + ea.z * w.z + ea.w * w.w;
                acc[1][j] += eb.x * w.x + eb.y * w.y + eb.z * w.z + eb.w * w.w;
            }
        }
    }
#pragma unroll
    for (int j = 0; j < 4; j++) {
        int hh = h0 + tx + j * 16;
        dst[((size_t)b * T + p0 + ty) * HDIM + hh]      = acc[0][j];
        dst[((size_t)b * T + p0 + ty + 16) * HDIM + hh] = acc[1][j];
    }
}

// ---------------------------------------------------------------------------
// BATCH-LOCAL attention: one block per batch, 512 threads, ZERO inter-block
// sync. Wr/Wt streamed from L2 (same 2MB shared by all blocks); a1/outp/a2q
// streamed per-block (L2/L3-resident). Per step:
//   1) a2 = a2q[t] + r.Wr^T ; tt = tanh(r.Wt^T)     (GEMV, 32 grp x 16 lanes)
//   2) s[p] = sum_h wv[h]*tanh(a1[p][h] + a2[h])    (8 lanes per p)
//   3) softmax over 128 p (in-block)
//   4) r[u] = tt[u] + sum_p score[p]*outp[p][u]     (coalesced u-major)
__global__ __launch_bounds__(512, 1) void att_batch(
    const float* __restrict__ a1b,   // [b][128][512]
    const float* __restrict__ a2qb,  // [b][64][512]
    const float* __restrict__ outp,  // [b][128][512]
    const float* __restrict__ Wr, const float* __restrict__ Wt,
    const float* __restrict__ wv,
    float* __restrict__ rout)        // [b][512]
{
    const int b = blockIdx.x;
    const int tid = threadIdx.x;
    const int g = tid >> 4, l = tid & 15;     // GEMV: 32 groups x 16 lanes
    const int pp = tid >> 3, tp = tid & 7;    // score: 64 p-slots x 8 lanes

    __shared__ __align__(16) float rsh[512];
    __shared__ __align__(16) float a2sh[512];
    __shared__ __align__(16) float ttsh[512];
    __shared__ __align__(16) float wvsh[512];
    __shared__ float ssh[128];
    __shared__ float scsh[128];
    __shared__ float red[4];

    const float* a1base = a1b + (size_t)b * 128 * 512;
    const float* opbase = outp + (size_t)b * 128 * 512;
    const float* a2qbase = a2qb + (size_t)b * 64 * 512;

    wvsh[tid] = wv[tid];
    rsh[tid] = 0.f;
    __syncthreads();

    for (int t = 0; t < HLEN; t++) {
        // ---- phase 1: a2 preload + GEMVs (r in registers, W streamed)
        a2sh[tid] = a2qbase[(size_t)t * 512 + tid];
        float4 rv[8];
        if (t > 0) {
#pragma unroll
            for (int kk = 0; kk < 8; kk++)
                rv[kk] = *(const float4*)&rsh[4 * l + 64 * kk];
        }
        __syncthreads();
        if (t > 0) {
#pragma unroll 1
            for (int j = 0; j < 16; j++) {
                const int u = g * 16 + j;
                const float4* wr = (const float4*)(Wr + (size_t)u * 512) + l;
                const float4* wt = (const float4*)(Wt + (size_t)u * 512) + l;
                float ar = 0.f, at = 0.f;
#pragma unroll
                for (int kk = 0; kk < 8; kk++) {
                    float4 w1 = wr[16 * kk];
                    float4 w2 = wt[16 * kk];
                    float4 r4 = rv[kk];
                    ar += w1.x * r4.x + w1.y * r4.y + w1.z * r4.z + w1.w * r4.w;
                    at += w2.x * r4.x + w2.y * r4.y + w2.z * r4.z + w2.w * r4.w;
                }
#pragma unroll
                for (int o = 1; o < 16; o <<= 1) {
                    ar += __shfl_xor(ar, o);
                    at += __shfl_xor(at, o);
                }
                if (l == 0) {
                    a2sh[u] += ar;
                    ttsh[u] = tanhfast(at);
                }
            }
        } else {
            ttsh[tid] = 0.f;
        }
        __syncthreads();

        // ---- phase 2: s[p] = sum_h wv[h] * tanh(a1[p][h] + a2[h])
#pragma unroll
        for (int pass = 0; pass < 2; pass++) {
            const int p = pass * 64 + pp;
            const float* a1p = a1base + (size_t)p * 512;
            float s = 0.f;
#pragma unroll
            for (int i = 0; i < 16; i++) {
                const int h0 = 4 * tp + 32 * i;
                float4 av = *(const float4*)(a1p + h0);
                float4 a2v = *(const float4*)&a2sh[h0];
                float4 wv4 = *(const float4*)&wvsh[h0];
                s += wv4.x * tanhfast(av.x + a2v.x)
                   + wv4.y * tanhfast(av.y + a2v.y)
                   + wv4.z * tanhfast(av.z + a2v.z)
                   + wv4.w * tanhfast(av.w + a2v.w);
            }
#pragma unroll
            for (int o = 1; o < 8; o <<= 1) s += __shfl_xor(s, o);
            if (tp == 0) ssh[p] = s;
        }
        __syncthreads();

        // ---- phase 3: softmax over 128 p
        float e = 0.f;
        if (tid < 128) {
            float s = ssh[tid];
            float m = s;
#pragma unroll
            for (int o = 1; o < 64; o <<= 1) m = fmaxf(m, __shfl_xor(m, o));
            if ((tid & 63) == 0) red[tid >> 6] = m;
        }
        __syncthreads();
        if (tid < 128) {
            float mx = fmaxf(red[0], red[1]);
            e = __expf(ssh[tid] - mx);
            float sm = e;
#pragma unroll
            for (int o = 1; o < 64; o <<= 1) sm += __shfl_xor(sm, o);
            if ((tid & 63) == 0) red[2 + (tid >> 6)] = sm;
        }
        __syncthreads();
        if (tid < 128) scsh[tid] = e / (red[2] + red[3]);
        __syncthreads();

        // ---- phase 4: r[u] = tt[u] + sum_p score[p] * outp[p][u]
        float acc = ttsh[tid];
        {
            const float* op = opbase + tid;
#pragma unroll 8
            for (int p = 0; p < 128; p++)
                acc += scsh[p] * op[(size_t)p * 512];
        }
        __syncthreads();   // everyone done reading rsh-dependent state
        rsh[tid] = acc;
        if (t == HLEN - 1) rout[(size_t)b * 512 + tid] = acc;
        __syncthreads();
    }
}

// ---------------------------------------------------------------------------
// final: rep = tanh(r.fc1^T + b1 + hn.fc2^T + b2); out = rep.fc3^T + b3
__global__ __launch_bounds__(256) void final_kernel(
    const float* __restrict__ r, const float* __restrict__ outh,
    const float* __restrict__ fc1w, const float* __restrict__ fc1b,
    const float* __restrict__ fc2w, const float* __restrict__ fc2b,
    const float* __restrict__ fc3w, const float* __restrict__ fc3b,
    float* __restrict__ out)
{
    int b = blockIdx.x, tid = threadIdx.x;
    __shared__ float rs[HDIM], hs[HDIM], rep[HDIM], red[256];
    for (int i = tid; i < 128; i += 256) {
        ((float4*)rs)[i] = ((const float4*)(r + (size_t)b * HDIM))[i];
        ((float4*)hs)[i] = ((const float4*)(outh + ((size_t)(b * HLEN + HLEN - 1)) * HDIM))[i];
    }
    __syncthreads();
    for (int u = tid; u < HDIM; u += 256) {
        const float4* w1 = (const float4*)(fc1w + (size_t)u * HDIM);
        const float4* w2 = (const float4*)(fc2w + (size_t)u * HDIM);
        float a = 0.f, bacc = 0.f;
        for (int k = 0; k < 128; k++) {
            float4 rv = ((float4*)rs)[k], hv = ((float4*)hs)[k];
            float4 x = w1[k]; a    += rv.x * x.x + rv.y * x.y + rv.z * x.z + rv.w * x.w;
            float4 y = w2[k]; bacc += hv.x * y.x + hv.y * y.y + hv.z * y.z + hv.w * y.w;
        }
        rep[u] = tanhfast(a + fc1b[u] + bacc + fc2b[u]);
    }
    __syncthreads();
    for (int cix = 0; cix < NCLS; cix++) {
        red[tid] = rep[tid] * fc3w[(size_t)cix * HDIM + tid]
                 + rep[tid + 256] * fc3w[(size_t)cix * HDIM + tid + 256];
        __syncthreads();
        for (int off = 128; off; off >>= 1) {
            if (tid < off) red[tid] += red[tid + off];
            __syncthreads();
        }
        if (tid == 0) out[b * NCLS + cix] = red[0] + fc3b[cix];
        __syncthreads();
    }
}

// ---------------------------------------------------------------------------
extern "C" void kernel_launch(void* const* d_in, const int* in_sizes, int n_in,
                              void* d_out, int out_size, void* d_ws, size_t ws_size,
                              hipStream_t stream)
{
    const int*   premise = (const int*)d_in[0];
    const int*   hyp     = (const int*)d_in[1];
    const float* emb     = (const float*)d_in[2];
    const float* Wih1    = (const float*)d_in[3];
    const float* Whh1    = (const float*)d_in[4];
    const float* bih1    = (const float*)d_in[5];
    const float* bhh1    = (const float*)d_in[6];
    const float* Wih2    = (const float*)d_in[7];
    const float* Whh2    = (const float*)d_in[8];
    const float* bih2    = (const float*)d_in[9];
    const float* bhh2    = (const float*)d_in[10];
    const float* Wy      = (const float*)d_in[11];
    const float* Wh      = (const float*)d_in[12];
    const float* Wr      = (const float*)d_in[13];
    const float* Wt      = (const float*)d_in[14];
    const float* wv      = (const float*)d_in[15];
    const float* fc1w    = (const float*)d_in[16];
    const float* fc1b    = (const float*)d_in[17];
    const float* fc2w    = (const float*)d_in[18];
    const float* fc2b    = (const float*)d_in[19];
    const float* fc3w    = (const float*)d_in[20];
    const float* fc3b    = (const float*)d_in[21];
    float* out = (float*)d_out;

    float* ws = (float*)d_ws;
    size_t off = 0;
    float* xp    = ws + off; off += (size_t)BSZ * PLEN * G4;   // dead after lstm
    float* xh    = ws + off; off += (size_t)BSZ * HLEN * G4;   // dead after lstm
    float* outp  = ws + off; off += (size_t)BSZ * PLEN * HDIM;
    float* outhp = ws + off; off += (size_t)BSZ * HLEN * HDIM;
    float* a1b   = ws + off; off += (size_t)BSZ * HDIM * PLEN; // [b][p][h]
    // aliases into dead regions (stream-ordered: written only after lstm)
    float* a2qb  = xp;                                          // 64*64*512
    float* rout  = xh;                                          // 64*512
    // lstm exchange buffers + done words
    unsigned long long* tbase = (unsigned long long*)(ws + off);
    unsigned long long* hAb   = tbase;                    // 16384 each (64*256)
    unsigned long long* hBb   = tbase + 16384;
    unsigned long long* hCb   = tbase + 2 * 16384;
    unsigned long long* hDb   = tbase + 3 * 16384;
    unsigned long long* dnH   = tbase + 4 * 16384;        // 256
    off += (size_t)(4 * 16384 + 256) * 2;                 // in floats
    if (ws_size < off * sizeof(float)) return;

    // zero ONLY the lstm done words (256 u64)
    ws_zero<<<dim3(1), dim3(256), 0, stream>>>(dnH);

    // input projections (biases folded in): 32x64 tiles
    proj_kernel<<<dim3(BSZ * PLEN / 32, G4 / 64), dim3(256), 0, stream>>>(
        premise, emb, Wih1, bih1, bhh1, xp);
    proj_kernel<<<dim3(BSZ * HLEN / 32, G4 / 64), dim3(256), 0, stream>>>(
        hyp, emb, Wih2, bih2, bhh2, xh);

    // both LSTMs, persistent, done-word sync (layer2 h via hC/hD)
    lstm_coop<<<dim3(256), dim3(256), 0, stream>>>(
        xp, xh, Whh1, Whh2, outp, outhp, hAb, hBb, hCb, hDb, dnH);

    // a1  = einsum('hj,bpj->bph', Wy, outp)   [b][128][512]
    a1_kernel<<<dim3(BSZ, PLEN / 32, HDIM / 64), dim3(256), 0, stream>>>(
        Wy, outp, a1b, PLEN);
    // a2q = einsum('hj,btj->bth', Wh, outh)   [b][64][512]
    a1_kernel<<<dim3(BSZ, HLEN / 32, HDIM / 64), dim3(256), 0, stream>>>(
        Wh, outhp, a2qb, HLEN);

    // batch-local attention recurrence: zero inter-block sync
    att_batch<<<dim3(BSZ), dim3(512), 0, stream>>>(
        a1b, a2qb, outp, Wr, Wt, wv, rout);

    // final classifier
    final_kernel<<<dim3(BSZ), dim3(256), 0, stream>>>(
        rout, outhp, fc1w, fc1b, fc2w, fc2b, fc3w, fc3b, out);
}

// Round 10
// 3141.382 us; speedup vs baseline: 1.2719x; 1.2719x over previous
//
#include <hip/hip_runtime.h>
#include <math.h>

#define BSZ 64
#define PLEN 128
#define HLEN 64
#define EDIM 300
#define HDIM 512
#define G4 2048   // 4*HDIM
#define NCLS 3

// spin guard: protocol bug degrades to wrong answer, not a hung container.
#define SPIN_CAP (1 << 18)

// 16-chunk 512-float vector layout: 16 chunks of 36 floats (32 data + 4 pad).
#define CR16 576
#define C16(f) ((((f) >> 5) * 36) + ((f) & 31))

__device__ __forceinline__ float sigf(float x) { return 1.0f / (1.0f + __expf(-x)); }
__device__ __forceinline__ float tanhfast(float x) { return 1.0f - 2.0f / (__expf(2.0f * x) + 1.0f); }

// relaxed agent-scope atomics: LLC-coherent, bypass non-coherent L1/L2
__device__ __forceinline__ unsigned long long aload64(const unsigned long long* p) {
    return __hip_atomic_load(p, __ATOMIC_RELAXED, __HIP_MEMORY_SCOPE_AGENT);
}
__device__ __forceinline__ void astore64(unsigned long long* p, unsigned long long v) {
    __hip_atomic_store(p, v, __ATOMIC_RELAXED, __HIP_MEMORY_SCOPE_AGENT);
}
__device__ __forceinline__ unsigned long long fpack2(float lo, float hi) {
    float2 v = make_float2(lo, hi);
    return *(unsigned long long*)&v;
}
__device__ __forceinline__ float2 funpack2(unsigned long long u) {
    union { unsigned long long u; float2 f; } c; c.u = u; return c.f;
}

__global__ __launch_bounds__(256) void ws_zero(unsigned long long* p) {
    p[(size_t)blockIdx.x * 256 + threadIdx.x] = 0ull;
}

// ---------------------------------------------------------------------------
// input projection GEMM: out[m][row] = emb[toks[m]] . Wih[row] + bih[row]+bhh[row]
__global__ __launch_bounds__(256) void proj_kernel(
    const int* __restrict__ toks, const float* __restrict__ emb,
    const float* __restrict__ Wih, const float* __restrict__ bih,
    const float* __restrict__ bhh, float* __restrict__ out)
{
    __shared__ float es[32 * 100];
    __shared__ float wsh[64 * 100];
    __shared__ int tks[32];
    const int m0 = blockIdx.x * 32, r0 = blockIdx.y * 64;
    const int tid = threadIdx.x;
    const int tx = tid & 15, ty = tid >> 4;
    float acc[2][4] = {{0.f, 0.f, 0.f, 0.f}, {0.f, 0.f, 0.f, 0.f}};
    if (tid < 32) tks[tid] = toks[m0 + tid];
    __syncthreads();
    for (int kc = 0; kc < 3; kc++) {
        if (kc) __syncthreads();
        for (int i = tid; i < 800; i += 256) {
            int row = i / 25, k4 = i % 25;
            ((float4*)es)[i] = ((const float4*)(emb + (size_t)tks[row] * EDIM + kc * 100))[k4];
        }
        for (int i = tid; i < 1600; i += 256) {
            int row = i / 25, k4 = i % 25;
            ((float4*)wsh)[i] = ((const float4*)(Wih + (size_t)(r0 + row) * EDIM + kc * 100))[k4];
        }
        __syncthreads();
        const float4* e0 = (const float4*)es + ty * 25;
        const float4* e1 = e0 + 16 * 25;
        const float4* w0 = (const float4*)wsh + tx * 25;
#pragma unroll
        for (int k = 0; k < 25; k++) {
            float4 ea = e0[k], eb = e1[k];
#pragma unroll
            for (int j = 0; j < 4; j++) {
                float4 w = w0[k + j * 400];
                acc[0][j] += ea.x * w.x + ea.y * w.y + ea.z * w.z + ea.w * w.w;
                acc[1][j] += eb.x * w.x + eb.y * w.y + eb.z * w.z + eb.w * w.w;
            }
        }
    }
#pragma unroll
    for (int j = 0; j < 4; j++) {
        int rr = r0 + tx + j * 16;
        float bsum = bih[rr] + bhh[rr];
        out[(size_t)(m0 + ty) * G4 + rr]      = acc[0][j] + bsum;
        out[(size_t)(m0 + ty + 16) * G4 + rr] = acc[1][j] + bsum;
    }
}

// ---------------------------------------------------------------------------
// persistent LSTM, done-word synced (R8 verbatim). 256 blocks x 256 threads.
__global__ __launch_bounds__(256, 1) void lstm_coop(
    const float* __restrict__ xp, const float* __restrict__ xh,
    const float* __restrict__ Whh1, const float* __restrict__ Whh2,
    float* __restrict__ outp, float* __restrict__ outh,
    unsigned long long* __restrict__ hA, unsigned long long* __restrict__ hB,
    unsigned long long* __restrict__ hC, unsigned long long* __restrict__ hD,
    unsigned long long* __restrict__ doneH)
{
    const int tid = threadIdx.x;
    const int ug = blockIdx.x >> 3;
    const int bg = blockIdx.x & 7;
    const int u0 = ug * 16, b0 = bg * 8;
    const int rq = tid >> 4, cc = tid & 15;

    __shared__ __align__(16) float hst[8 * CR16];
    __shared__ float gsm[64][9];

    float4 w4[32];
#pragma unroll
    for (int j = 0; j < 4; j++) {
        int rr = 4 * rq + j;
        const float4* src = (const float4*)(Whh1 +
            ((size_t)((rr >> 4) * HDIM + u0 + (rr & 15))) * HDIM) + cc * 8;
#pragma unroll
        for (int q = 0; q < 8; q++) w4[j * 8 + q] = src[q];
    }
    float creg = 0.0f;
    const int bbc = tid >> 4, uuc = tid & 15;
    unsigned long long* dn = doneH + bg * 32;

    for (int t = 0; t < PLEN + HLEN; t++) {
        const int layer2 = (t >= PLEN) ? 1 : 0;
        const int tloc = layer2 ? t - PLEN : t;
        const int T = layer2 ? HLEN : PLEN;
        const float* xproj = layer2 ? xh : xp;
        float* outseq = layer2 ? outh : outp;
        unsigned long long* wA = layer2 ? hC : hA;
        unsigned long long* wB = layer2 ? hD : hB;
        unsigned long long* hwr = (t & 1) ? wB : wA;
        const unsigned long long* hrd = (t & 1) ? wA : wB;

        float gi = 0.f, gf = 0.f, gg = 0.f, go = 0.f;
        if (tid < 128) {
            size_t xb = ((size_t)(b0 + bbc) * T + tloc) * G4 + u0 + uuc;
            gi = xproj[xb];        gf = xproj[xb + 512];
            gg = xproj[xb + 1024]; go = xproj[xb + 1536];
        }

        if (t == PLEN) {
#pragma unroll
            for (int j = 0; j < 4; j++) {
                int rr = 4 * rq + j;
                const float4* src = (const float4*)(Whh2 +
                    ((size_t)((rr >> 4) * HDIM + u0 + (rr & 15))) * HDIM) + cc * 8;
#pragma unroll
                for (int q = 0; q < 8; q++) w4[j * 8 + q] = src[q];
            }
        }
        const bool have_h = (tloc != 0);
        if (have_h) {
            if (tid < 32) {
                unsigned long long v = aload64(dn + tid);
                int guard = 0;
                while (!__all(v >= (unsigned long long)t)) {
                    if (++guard > SPIN_CAP) break;
                    __builtin_amdgcn_s_sleep(1);
                    if (v < (unsigned long long)t) v = aload64(dn + tid);
                }
            }
            __syncthreads();
            __asm__ volatile("" ::: "memory");
            const unsigned long long* src = hrd + (size_t)b0 * 256;
            unsigned long long v[8];
#pragma unroll
            for (int i = 0; i < 8; i++) v[i] = aload64(src + tid + i * 256);
#pragma unroll
            for (int i = 0; i < 8; i++) {
                int idx = tid + i * 256;
                int bb = idx >> 8, j = idx & 255;
                float2 f = funpack2(v[i]);
                *(float2*)&hst[bb * CR16 + C16(2 * j)] = f;
            }
            __syncthreads();
#pragma unroll 1
            for (int bb = 0; bb < 8; bb++) {
                const float* hb = &hst[bb * CR16 + cc * 36];
                float a0 = 0.f, a1 = 0.f, a2 = 0.f, a3 = 0.f;
#pragma unroll
                for (int q = 0; q < 8; q++) {
                    float4 hv = *(const float4*)(hb + 4 * q);
                    float4 x;
                    x = w4[q];      a0 += x.x * hv.x + x.y * hv.y + x.z * hv.z + x.w * hv.w;
                    x = w4[8 + q];  a1 += x.x * hv.x + x.y * hv.y + x.z * hv.z + x.w * hv.w;
                    x = w4[16 + q]; a2 += x.x * hv.x + x.y * hv.y + x.z * hv.z + x.w * hv.w;
                    x = w4[24 + q]; a3 += x.x * hv.x + x.y * hv.y + x.z * hv.z + x.w * hv.w;
                }
#pragma unroll
                for (int o = 1; o < 16; o <<= 1) {
                    a0 += __shfl_xor(a0, o);
                    a1 += __shfl_xor(a1, o);
                    a2 += __shfl_xor(a2, o);
                    a3 += __shfl_xor(a3, o);
                }
                if (cc == 0) {
                    gsm[4 * rq + 0][bb] = a0;
                    gsm[4 * rq + 1][bb] = a1;
                    gsm[4 * rq + 2][bb] = a2;
                    gsm[4 * rq + 3][bb] = a3;
                }
            }
        }
        __syncthreads();
        float hn = 0.f;
        if (tid < 128) {
            if (have_h) {
                gi += gsm[uuc][bbc];
                gf += gsm[16 + uuc][bbc];
                gg += gsm[32 + uuc][bbc];
                go += gsm[48 + uuc][bbc];
            }
            float cn = sigf(gf) * creg + sigf(gi) * tanhfast(gg);
            hn = sigf(go) * tanhfast(cn);
            creg = cn;
            float pr = __shfl_xor(hn, 1);
            if ((uuc & 1) == 0)
                astore64(hwr + (size_t)(b0 + bbc) * 256 + (u0 + uuc) / 2, fpack2(hn, pr));
        }
        __asm__ volatile("s_waitcnt vmcnt(0)" ::: "memory");
        __syncthreads();
        if (tid == 0) astore64(&dn[ug], (unsigned long long)(t + 1));
        if (tid < 128)
            outseq[((size_t)(b0 + bbc) * T + tloc) * HDIM + u0 + uuc] = hn;
    }
}

// ---------------------------------------------------------------------------
// generic projection GEMM: dst[b][p][h] = sum_j W[h][j] * src[b][p][j]
// Used for a1 (T=128, W=Wy) and a2q (T=64, W=Wh).
__global__ __launch_bounds__(256) void a1_kernel(
    const float* __restrict__ W, const float* __restrict__ src,
    float* __restrict__ dst, int T)
{
    __shared__ float os[32 * 132];
    __shared__ float wsh[64 * 132];
    const int b = blockIdx.x, p0 = blockIdx.y * 32, h0 = blockIdx.z * 64;
    const int tid = threadIdx.x;
    const int tx = tid & 15, ty = tid >> 4;
    float acc[2][4] = {{0.f, 0.f, 0.f, 0.f}, {0.f, 0.f, 0.f, 0.f}};
    for (int kc = 0; kc < 4; kc++) {
        if (kc) __syncthreads();
        for (int i = tid; i < 1024; i += 256) {
            int row = i >> 5, k4 = i & 31;
            ((float4*)os)[row * 33 + k4] =
                ((const float4*)(src + ((size_t)(b * T) + p0 + row) * HDIM + kc * 128))[k4];
        }
        for (int i = tid; i < 2048; i += 256) {
            int row = i >> 5, k4 = i & 31;
            ((float4*)wsh)[row * 33 + k4] =
                ((const float4*)(W + (size_t)(h0 + row) * HDIM + kc * 128))[k4];
        }
        __syncthreads();
        const float4* o0 = (const float4*)os + ty * 33;
        const float4* o1 = o0 + 16 * 33;
        const float4* w0 = (const float4*)wsh + tx * 33;
#pragma unroll
        for (int k = 0; k < 32; k++) {
            float4 ea = o0[k], eb = o1[k];
#pragma unroll
            for (int j = 0; j < 4; j++) {
                float4 w = w0[k + j * 528];
                acc[0][j] += ea.x * w.x + ea.y * w.y + ea.z * w.z + ea.w * w.w;
                acc[1][j] += eb.x * w.x + eb.y * w.y + eb.z * w.z + eb.w * w.w;
            }
        }
    }
#pragma unroll
    for (int j = 0; j < 4; j++) {
        int hh = h0 + tx + j * 16;
        dst[((size_t)b * T + p0 + ty) * HDIM + hh]      = acc[0][j];
        dst[((size_t)b * T + p0 + ty + 16) * HDIM + hh] = acc[1][j];
    }
}

// ---------------------------------------------------------------------------
// persistent attention v2: TWO exchanges per step (was 3, with full-a2
// broadcast). Block (ug, bg): 16 h-units, 8 batches. Wr/Wt rows in VGPRs;
// a1 slice [8b][4p][16h] per THREAD in registers; outp slice in LDS.
// Per step: local a2-slice GEMV -> local partial-s over ALL 128 p ->
// exchange partial-s (sum of 32 read from LLC) -> local softmax ->
// local r-update -> exchange r.
#define OSTR 2056   // 128*16 + 8 pad
__global__ __launch_bounds__(256, 1) void att_coop2(
    const float* __restrict__ a1b,   // [b][128][512]
    const float* __restrict__ a2qb,  // [b][64][512]  (q.Wh^T, precomputed)
    const float* __restrict__ outp,  // [b][128][512]
    const float* __restrict__ Wr, const float* __restrict__ Wt,
    const float* __restrict__ wv,
    unsigned long long* __restrict__ rA, unsigned long long* __restrict__ rB,
    unsigned long long* __restrict__ sPart,  // [2][bg][ug][b][64] u64
    unsigned long long* __restrict__ dnS, unsigned long long* __restrict__ dnR)
{
    const int tid = threadIdx.x;
    const int ug = blockIdx.x >> 3;
    const int bg = blockIdx.x & 7;
    const int u0 = ug * 16, b0 = bg * 8;
    const int rp = tid >> 4, cc = tid & 15;   // GEMV: row-pair (Wr[rp],Wt[rp]) x chunk
    const int ab = tid >> 5, aq = tid & 31;   // partial-s: batch, p-quad

    __shared__ __align__(16) float rst[8 * CR16];   // chunked r staging
    __shared__ __align__(16) float ops[8 * OSTR];   // persistent outp slice
    __shared__ __align__(16) float scst[8][132];
    __shared__ float a2sl[16][9];
    __shared__ float ttsl[16][9];
    __shared__ float wvs[16];

    // weights: Wr row rp + Wt row rp, chunk cc (32 floats = 8 f4 each)
    float4 wr4[8], wt4[8];
    {
        const float4* sr = (const float4*)(Wr + (size_t)(u0 + rp) * HDIM) + cc * 8;
        const float4* st = (const float4*)(Wt + (size_t)(u0 + rp) * HDIM) + cc * 8;
#pragma unroll
        for (int q = 0; q < 8; q++) { wr4[q] = sr[q]; wt4[q] = st[q]; }
    }
    if (tid < 16) wvs[tid] = wv[u0 + tid];

    // one-time: outp slice -> LDS
    for (int i = tid; i < 8 * 128 * 4; i += 256) {
        int bb = i >> 9;
        int rem = i & 511;
        int p = rem >> 2, q = rem & 3;
        float4 v = *((const float4*)(outp + ((size_t)(b0 + bb) * PLEN + p) * HDIM + u0) + q);
        *((float4*)(ops + bb * OSTR + p * 16) + q) = v;
    }
    // one-time: a1 slice -> regs: thread (ab, aq): p = 4aq..4aq+3, h = u0..u0+15
    float4 a1r[4][4];
#pragma unroll
    for (int p = 0; p < 4; p++) {
        const float4* src = (const float4*)(a1b +
            ((size_t)(b0 + ab) * PLEN + 4 * aq + p) * HDIM + u0);
#pragma unroll
        for (int k = 0; k < 4; k++) a1r[p][k] = src[k];
    }
    __syncthreads();

    unsigned long long* myS = dnS + bg * 32;
    unsigned long long* myR = dnR + bg * 32;
    const int bbc = tid >> 4, uuc = tid & 15;

    for (int t = 0; t < HLEN; t++) {
        unsigned long long* rwr = (t & 1) ? rB : rA;
        const unsigned long long* rrd = (t & 1) ? rA : rB;
        unsigned long long* sp = sPart + ((size_t)((t & 1) * 8 + bg)) * 16384;

        // a2 init from precomputed a2q (tid<128: b=tid>>4, h=tid&15)
        if (tid < 128) {
            int b = tid >> 4, hh = tid & 15;
            a2sl[hh][b] = a2qb[((size_t)(b0 + b) * HLEN + t) * HDIM + u0 + hh];
            ttsl[hh][b] = 0.f;
        }
        if (t > 0) {
            // exchange 2 (prev step): poll dnR >= t, then load r once
            if (tid < 32) {
                unsigned long long v = aload64(myR + tid);
                int guard = 0;
                while (!__all(v >= (unsigned long long)t)) {
                    if (++guard > SPIN_CAP) break;
                    __builtin_amdgcn_s_sleep(1);
                    if (v < (unsigned long long)t) v = aload64(myR + tid);
                }
            }
            __syncthreads();
            __asm__ volatile("" ::: "memory");
            const unsigned long long* src = rrd + (size_t)b0 * 256;
            unsigned long long v[8];
#pragma unroll
            for (int i = 0; i < 8; i++) v[i] = aload64(src + tid + i * 256);
#pragma unroll
            for (int i = 0; i < 8; i++) {
                int idx = tid + i * 256;
                int bb = idx >> 8, j = idx & 255;
                float2 f = funpack2(v[i]);
                *(float2*)&rst[bb * CR16 + C16(2 * j)] = f;
            }
        }
        __syncthreads();
        if (t > 0) {
            // local GEMV: a2sl[rp][b] += (r.Wr)[u0+rp]; ttsl = tanh((r.Wt)[u0+rp])
#pragma unroll 1
            for (int b = 0; b < 8; b++) {
                const float* hb = &rst[b * CR16 + cc * 36];
                float ar = 0.f, at = 0.f;
#pragma unroll
                for (int q = 0; q < 8; q++) {
                    float4 hv = *(const float4*)(hb + 4 * q);
                    float4 x = wr4[q], y = wt4[q];
                    ar += x.x * hv.x + x.y * hv.y + x.z * hv.z + x.w * hv.w;
                    at += y.x * hv.x + y.y * hv.y + y.z * hv.z + y.w * hv.w;
                }
#pragma unroll
                for (int o = 1; o < 16; o <<= 1) {
                    ar += __shfl_xor(ar, o);
                    at += __shfl_xor(at, o);
                }
                if (cc == 0) {
                    a2sl[rp][b] += ar;
                    ttsl[rp][b] = tanhfast(at);
                }
            }
        }
        __syncthreads();
        // local partial-s over all 128 p (thread: batch ab, p-quad aq)
        {
            float s4[4];
#pragma unroll
            for (int p = 0; p < 4; p++) {
                float s = 0.f;
#pragma unroll
                for (int k = 0; k < 4; k++) {
                    float4 av = a1r[p][k];
                    s += wvs[4 * k + 0] * tanhfast(av.x + a2sl[4 * k + 0][ab])
                       + wvs[4 * k + 1] * tanhfast(av.y + a2sl[4 * k + 1][ab])
                       + wvs[4 * k + 2] * tanhfast(av.z + a2sl[4 * k + 2][ab])
                       + wvs[4 * k + 3] * tanhfast(av.w + a2sl[4 * k + 3][ab]);
                }
                s4[p] = s;
            }
            unsigned long long* d = sp + ((size_t)ug * 8 + ab) * 64 + aq * 2;
            astore64(d, fpack2(s4[0], s4[1]));
            astore64(d + 1, fpack2(s4[2], s4[3]));
        }
        __asm__ volatile("s_waitcnt vmcnt(0)" ::: "memory");
        __syncthreads();
        if (tid == 0) astore64(&myS[ug], (unsigned long long)(t + 1));

        // exchange 1: poll dnS, then sum 32 partials
        {
            if (tid < 32) {
                unsigned long long v = aload64(myS + tid);
                int guard = 0;
                while (!__all(v >= (unsigned long long)(t + 1))) {
                    if (++guard > SPIN_CAP) break;
                    __builtin_amdgcn_s_sleep(1);
                    if (v < (unsigned long long)(t + 1)) v = aload64(myS + tid);
                }
            }
            __syncthreads();
            __asm__ volatile("" ::: "memory");
#pragma unroll
            for (int i = 0; i < 2; i++) {
                int idx = tid + i * 256;
                int b = idx >> 6, p2 = idx & 63;
                float sx = 0.f, sy = 0.f;
#pragma unroll 8
                for (int g = 0; g < 32; g++) {
                    float2 f = funpack2(aload64(sp + ((size_t)g * 8 + b) * 64 + p2));
                    sx += f.x; sy += f.y;
                }
                scst[b][2 * p2] = sx;
                scst[b][2 * p2 + 1] = sy;
            }
        }
        __syncthreads();
        // local softmax over 128 p per batch
        {
            const int bb = tid >> 5, j = tid & 31;
            float4 v = *(float4*)&scst[bb][j * 4];
            float mx = fmaxf(fmaxf(v.x, v.y), fmaxf(v.z, v.w));
#pragma unroll
            for (int o = 1; o < 32; o <<= 1) mx = fmaxf(mx, __shfl_xor(mx, o));
            float ex = __expf(v.x - mx), ey = __expf(v.y - mx);
            float ez = __expf(v.z - mx), ew = __expf(v.w - mx);
            float ssum = (ex + ey) + (ez + ew);
#pragma unroll
            for (int o = 1; o < 32; o <<= 1) ssum += __shfl_xor(ssum, o);
            float inv = 1.0f / ssum;
            float4 sc4 = make_float4(ex * inv, ey * inv, ez * inv, ew * inv);
            *(float4*)&scst[bb][j * 4] = sc4;
        }
        __syncthreads();
        // local r-update + exchange 2 store
        if (tid < 128) {
            float acc = ttsl[uuc][bbc];
            const float* opb = ops + bbc * OSTR + uuc;
#pragma unroll 8
            for (int p = 0; p < PLEN; p++)
                acc += scst[bbc][p] * opb[p * 16];
            float pr = __shfl_xor(acc, 1);
            if ((uuc & 1) == 0)
                astore64(rwr + (size_t)(b0 + bbc) * 256 + (u0 + uuc) / 2, fpack2(acc, pr));
        }
        __asm__ volatile("s_waitcnt vmcnt(0)" ::: "memory");
        __syncthreads();
        if (tid == 0) astore64(&myR[ug], (unsigned long long)(t + 1));
    }
}

// ---------------------------------------------------------------------------
// final: rep = tanh(r.fc1^T + b1 + hn.fc2^T + b2); out = rep.fc3^T + b3
// r read from packed-float2 u64 buffer.
__global__ __launch_bounds__(256) void final_kernel(
    const unsigned long long* __restrict__ r2, const float* __restrict__ outh,
    const float* __restrict__ fc1w, const float* __restrict__ fc1b,
    const float* __restrict__ fc2w, const float* __restrict__ fc2b,
    const float* __restrict__ fc3w, const float* __restrict__ fc3b,
    float* __restrict__ out)
{
    int b = blockIdx.x, tid = threadIdx.x;
    __shared__ float rs[HDIM], hs[HDIM], rep[HDIM], red[256];
    {
        float2 f = funpack2(r2[(size_t)b * 256 + tid]);
        rs[2 * tid] = f.x; rs[2 * tid + 1] = f.y;
    }
    for (int i = tid; i < 128; i += 256)
        ((float4*)hs)[i] = ((const float4*)(outh + ((size_t)(b * HLEN + HLEN - 1)) * HDIM))[i];
    __syncthreads();
    for (int u = tid; u < HDIM; u += 256) {
        const float4* w1 = (const float4*)(fc1w + (size_t)u * HDIM);
        const float4* w2 = (const float4*)(fc2w + (size_t)u * HDIM);
        float a = 0.f, bacc = 0.f;
        for (int k = 0; k < 128; k++) {
            float4 rv = ((float4*)rs)[k], hv = ((float4*)hs)[k];
            float4 x = w1[k]; a    += rv.x * x.x + rv.y * x.y + rv.z * x.z + rv.w * x.w;
            float4 y = w2[k]; bacc += hv.x * y.x + hv.y * y.y + hv.z * y.z + hv.w * y.w;
        }
        rep[u] = tanhfast(a + fc1b[u] + bacc + fc2b[u]);
    }
    __syncthreads();
    for (int cix = 0; cix < NCLS; cix++) {
        red[tid] = rep[tid] * fc3w[(size_t)cix * HDIM + tid]
                 + rep[tid + 256] * fc3w[(size_t)cix * HDIM + tid + 256];
        __syncthreads();
        for (int off = 128; off; off >>= 1) {
            if (tid < off) red[tid] += red[tid + off];
            __syncthreads();
        }
        if (tid == 0) out[b * NCLS + cix] = red[0] + fc3b[cix];
        __syncthreads();
    }
}

// ---------------------------------------------------------------------------
extern "C" void kernel_launch(void* const* d_in, const int* in_sizes, int n_in,
                              void* d_out, int out_size, void* d_ws, size_t ws_size,
                              hipStream_t stream)
{
    const int*   premise = (const int*)d_in[0];
    const int*   hyp     = (const int*)d_in[1];
    const float* emb     = (const float*)d_in[2];
    const float* Wih1    = (const float*)d_in[3];
    const float* Whh1    = (const float*)d_in[4];
    const float* bih1    = (const float*)d_in[5];
    const float* bhh1    = (const float*)d_in[6];
    const float* Wih2    = (const float*)d_in[7];
    const float* Whh2    = (const float*)d_in[8];
    const float* bih2    = (const float*)d_in[9];
    const float* bhh2    = (const float*)d_in[10];
    const float* Wy      = (const float*)d_in[11];
    const float* Wh      = (const float*)d_in[12];
    const float* Wr      = (const float*)d_in[13];
    const float* Wt      = (const float*)d_in[14];
    const float* wv      = (const float*)d_in[15];
    const float* fc1w    = (const float*)d_in[16];
    const float* fc1b    = (const float*)d_in[17];
    const float* fc2w    = (const float*)d_in[18];
    const float* fc2b    = (const float*)d_in[19];
    const float* fc3w    = (const float*)d_in[20];
    const float* fc3b    = (const float*)d_in[21];
    float* out = (float*)d_out;

    float* ws = (float*)d_ws;
    size_t off = 0;
    float* xp    = ws + off; off += (size_t)BSZ * PLEN * G4;   // dead after lstm
    float* xh    = ws + off; off += (size_t)BSZ * HLEN * G4;   // dead after lstm
    float* outp  = ws + off; off += (size_t)BSZ * PLEN * HDIM;
    float* outhp = ws + off; off += (size_t)BSZ * HLEN * HDIM;
    float* a1b   = ws + off; off += (size_t)BSZ * HDIM * PLEN; // [b][p][h]
    // alias into dead xp region (written only after lstm completes)
    float* a2qb  = xp;                                          // 64*64*512
    // exchange buffers + done words
    unsigned long long* tbase = (unsigned long long*)(ws + off);
    unsigned long long* hAb   = tbase;                    // 16384 each (64*256)
    unsigned long long* hBb   = tbase + 16384;
    unsigned long long* hCb   = tbase + 2 * 16384;        // also att rA
    unsigned long long* hDb   = tbase + 3 * 16384;        // also att rB
    unsigned long long* sPart = tbase + 4 * 16384;        // 2*8*16384 = 262144
    unsigned long long* dnH   = sPart + 262144;           // 256 each
    unsigned long long* dnS   = dnH + 256;
    unsigned long long* dnR   = dnS + 256;
    off += (size_t)(4 * 16384 + 262144 + 768) * 2;        // in floats
    if (ws_size < off * sizeof(float)) return;

    // zero the done words (768 u64 = 3 * 256)
    ws_zero<<<dim3(3), dim3(256), 0, stream>>>(dnH);

    // input projections (biases folded in): 32x64 tiles
    proj_kernel<<<dim3(BSZ * PLEN / 32, G4 / 64), dim3(256), 0, stream>>>(
        premise, emb, Wih1, bih1, bhh1, xp);
    proj_kernel<<<dim3(BSZ * HLEN / 32, G4 / 64), dim3(256), 0, stream>>>(
        hyp, emb, Wih2, bih2, bhh2, xh);

    // both LSTMs, persistent, done-word sync (layer2 h via hC/hD)
    lstm_coop<<<dim3(256), dim3(256), 0, stream>>>(
        xp, xh, Whh1, Whh2, outp, outhp, hAb, hBb, hCb, hDb, dnH);

    // a1  = einsum('hj,bpj->bph', Wy, outp)   [b][128][512]
    a1_kernel<<<dim3(BSZ, PLEN / 32, HDIM / 64), dim3(256), 0, stream>>>(
        Wy, outp, a1b, PLEN);
    // a2q = einsum('hj,btj->bth', Wh, outh)   [b][64][512]
    a1_kernel<<<dim3(BSZ, HLEN / 32, HDIM / 64), dim3(256), 0, stream>>>(
        Wh, outhp, a2qb, HLEN);

    // attention recurrence v2: 2 exchanges/step (partial-s + r)
    att_coop2<<<dim3(256), dim3(256), 0, stream>>>(
        a1b, a2qb, outp, Wr, Wt, wv, hCb, hDb, sPart, dnS, dnR);

    // final classifier: r after step 63 lives in rB (63 & 1 == 1) = hDb
    final_kernel<<<dim3(BSZ), dim3(256), 0, stream>>>(
        hDb, outhp, fc1w, fc1b, fc2w, fc2b, fc3w, fc3b, out);
}